// Round 7
// baseline (140.031 us; speedup 1.0000x reference)
//
#include <hip/hip_runtime.h>
#include <math.h>

__device__ __forceinline__ float silu_act(float y) {
    return y / (1.f + __expf(-y));
}

// Pointwise 1x1 conv + scale/bias + SiLU. Compile-time Cin for full unroll.
template<int TC, int CIN>
__global__ void pw_conv_silu(const float* __restrict__ in, int HW, int B,
                             const float* __restrict__ w,
                             const float* __restrict__ sc, const float* __restrict__ bi,
                             float* __restrict__ out, int CoutStride) {
    int g = blockIdx.x * blockDim.x + threadIdx.x;
    if (g >= B * HW) return;
    int b = g / HW, pix = g - b * HW;
    int co0 = blockIdx.y * TC;
    float acc[TC];
#pragma unroll
    for (int j = 0; j < TC; ++j) acc[j] = 0.f;
    const float* ip = in + (size_t)b * CIN * HW + pix;
    const float* wp = w + (size_t)co0 * CIN;
#pragma unroll 8
    for (int ci = 0; ci < CIN; ++ci) {
        float v = ip[(size_t)ci * HW];
#pragma unroll
        for (int j = 0; j < TC; ++j)
            acc[j] = fmaf(v, wp[j * CIN + ci], acc[j]);
    }
#pragma unroll
    for (int j = 0; j < TC; ++j) {
        int co = co0 + j;
        float y = fmaf(acc[j], sc[co], bi[co]);
        out[((size_t)b * CoutStride + co) * HW + pix] = silu_act(y);
    }
}

// fusedA: comp dw3/dw5 + comp px (1x1) + enc cv1 (1x1), one image row per block.
// Block = (Y, b), 256 threads = (l = t&63 pixel, g = t>>6 wave-uniform group).
// In: x1c [b][32][4096] (comp cv1 output). Out: x1e [b][50][4096].
__global__ __launch_bounds__(256) void fusedA_kernel(
        const float* __restrict__ x1c,
        const float* __restrict__ w3, const float* __restrict__ s3, const float* __restrict__ b3,
        const float* __restrict__ w5, const float* __restrict__ s5, const float* __restrict__ b5,
        const float* __restrict__ pxw, const float* __restrict__ pxs, const float* __restrict__ pxb,
        const float* __restrict__ ew, const float* __restrict__ es, const float* __restrict__ eb,
        float* __restrict__ x1e) {
    const int H = 64, Wd = 64, HW = 4096;
    int Y = blockIdx.x, b = blockIdx.y;
    __shared__ float xs[32][5][68];    // x1c rows Y-2..Y+2, zero-padded cols (col = ix+2)
    __shared__ float cat[64][64];      // [ci][l]: x1 (0..31), x2=dw (32..63)
    __shared__ float yrow[64][64];     // comp px output [co][l]
    int t = threadIdx.x;
    const float* src = x1c + (size_t)b * 32 * HW;
    for (int i = t; i < 32 * 5 * 68; i += 256) {
        int col = i % 68;
        int tmp = i / 68;
        int p = tmp % 5;
        int c = tmp / 5;
        int iy = Y + p - 2, ix = col - 2;
        float v = 0.f;
        if ((unsigned)iy < (unsigned)H && (unsigned)ix < (unsigned)Wd)
            v = src[(size_t)c * HW + iy * Wd + ix];
        xs[c][p][col] = v;
    }
    __syncthreads();
    int l = t & 63;
    int g = t >> 6;
    // depthwise: c = g*8 .. g*8+7; c<16 -> k3 (w3[c]), else k5 (w5[c-16])
#pragma unroll
    for (int k = 0; k < 8; ++k) {
        int c = g * 8 + k;
        float acc = 0.f, sc, bi;
        if (c < 16) {
            const float* wk = w3 + c * 9;
#pragma unroll
            for (int p = 0; p < 3; ++p)
#pragma unroll
                for (int q = 0; q < 3; ++q)
                    acc = fmaf(xs[c][p + 1][l + 1 + q], wk[p * 3 + q], acc);
            sc = s3[c]; bi = b3[c];
        } else {
            const float* wk = w5 + (c - 16) * 25;
#pragma unroll
            for (int p = 0; p < 5; ++p)
#pragma unroll
                for (int q = 0; q < 5; ++q)
                    acc = fmaf(xs[c][p][l + q], wk[p * 5 + q], acc);
            sc = s5[c - 16]; bi = b5[c - 16];
        }
        cat[32 + c][l] = silu_act(fmaf(acc, sc, bi));
        cat[c][l] = xs[c][2][l + 2];   // x1 row Y
    }
    __syncthreads();
    // comp px: thread computes co = g*16 .. g*16+15
    {
        float acc[16];
#pragma unroll
        for (int k = 0; k < 16; ++k) acc[k] = 0.f;
#pragma unroll 4
        for (int ci = 0; ci < 64; ++ci) {
            float xv = cat[ci][l];
#pragma unroll
            for (int k = 0; k < 16; ++k)
                acc[k] = fmaf(xv, pxw[(g * 16 + k) * 64 + ci], acc[k]);
        }
#pragma unroll
        for (int k = 0; k < 16; ++k) {
            int co = g * 16 + k;
            yrow[co][l] = silu_act(fmaf(acc[k], pxs[co], pxb[co]));
        }
    }
    __syncthreads();
    // enc cv1: thread computes ce = j*4 + g (j = 0..12, ce < 50)
    {
        float acc[13];
#pragma unroll
        for (int j = 0; j < 13; ++j) acc[j] = 0.f;
#pragma unroll 4
        for (int co = 0; co < 64; ++co) {
            float yv = yrow[co][l];
#pragma unroll
            for (int j = 0; j < 13; ++j) {
                int ce = j * 4 + g;
                if (ce < 50)
                    acc[j] = fmaf(yv, ew[ce * 64 + co], acc[j]);
            }
        }
        float* dst = x1e + (size_t)b * 50 * HW + Y * Wd + l;
#pragma unroll
        for (int j = 0; j < 13; ++j) {
            int ce = j * 4 + g;
            if (ce < 50)
                dst[(size_t)ce * HW] = silu_act(fmaf(acc[j], es[ce], eb[ce]));
        }
    }
}

// fusedB: enc dw3/dw5 + enc px (1x1) + softmax + pixel-shuffle transpose.
// Block = (Y, b); thread (l, g): computes enc-px channels co = j*4+g (the 25
// taps of rp-group g at pixel (Y,l)), softmaxes in-register, writes
// ws[b][Y][g][j][l].
__global__ __launch_bounds__(256) void fusedB_kernel(
        const float* __restrict__ x1e,
        const float* __restrict__ w3, const float* __restrict__ s3, const float* __restrict__ b3,
        const float* __restrict__ w5, const float* __restrict__ s5, const float* __restrict__ b5,
        const float* __restrict__ pxw, const float* __restrict__ pxs, const float* __restrict__ pxb,
        float* __restrict__ ws) {
    const int H = 64, Wd = 64, HW = 4096;
    int Y = blockIdx.x, b = blockIdx.y;
    __shared__ float xs[50][5][68];    // x1e rows Y-2..Y+2, zero-padded cols
    __shared__ float cat[100][64];     // [ci][l]: x1e (0..49), x2e=dw (50..99)
    int t = threadIdx.x;
    const float* src = x1e + (size_t)b * 50 * HW;
    for (int i = t; i < 50 * 5 * 68; i += 256) {
        int col = i % 68;
        int tmp = i / 68;
        int p = tmp % 5;
        int c = tmp / 5;
        int iy = Y + p - 2, ix = col - 2;
        float v = 0.f;
        if ((unsigned)iy < (unsigned)H && (unsigned)ix < (unsigned)Wd)
            v = src[(size_t)c * HW + iy * Wd + ix];
        xs[c][p][col] = v;
    }
    __syncthreads();
    int l = t & 63;
    int g = t >> 6;
    // depthwise: c in [g*25/2, (g+1)*25/2); c<25 -> k3 (w3[c]), else k5 (w5[c-25])
    int cb0 = (g * 25) >> 1, cb1 = ((g + 1) * 25) >> 1;
    for (int c = cb0; c < cb1; ++c) {
        float acc = 0.f, sc, bi;
        if (c < 25) {
            const float* wk = w3 + c * 9;
#pragma unroll
            for (int p = 0; p < 3; ++p)
#pragma unroll
                for (int q = 0; q < 3; ++q)
                    acc = fmaf(xs[c][p + 1][l + 1 + q], wk[p * 3 + q], acc);
            sc = s3[c]; bi = b3[c];
        } else {
            const float* wk = w5 + (c - 25) * 25;
#pragma unroll
            for (int p = 0; p < 5; ++p)
#pragma unroll
                for (int q = 0; q < 5; ++q)
                    acc = fmaf(xs[c][p][l + q], wk[p * 5 + q], acc);
            sc = s5[c - 25]; bi = b5[c - 25];
        }
        cat[50 + c][l] = silu_act(fmaf(acc, sc, bi));
        cat[c][l] = xs[c][2][l + 2];   // x1e row Y
    }
    __syncthreads();
    // enc px (co = j*4+g) + BN + SiLU + softmax over j
    float acc[25];
#pragma unroll
    for (int j = 0; j < 25; ++j) acc[j] = 0.f;
#pragma unroll 4
    for (int ci = 0; ci < 100; ++ci) {
        float xv = cat[ci][l];
#pragma unroll
        for (int j = 0; j < 25; ++j)
            acc[j] = fmaf(xv, pxw[(j * 4 + g) * 100 + ci], acc[j]);
    }
    float m = -1e30f;
#pragma unroll
    for (int j = 0; j < 25; ++j) {
        int co = j * 4 + g;
        acc[j] = silu_act(fmaf(acc[j], pxs[co], pxb[co]));
        m = fmaxf(m, acc[j]);
    }
    float s = 0.f;
#pragma unroll
    for (int j = 0; j < 25; ++j) { acc[j] = __expf(acc[j] - m); s += acc[j]; }
    float inv = 1.f / s;
    float* dst = ws + ((((size_t)b * 64 + Y) * 4 + g) * 25) * 64 + l;
#pragma unroll
    for (int j = 0; j < 25; ++j) dst[j * 64] = acc[j] * inv;
}

// CARAFE v5: pre-softmaxed weights from ws; zero-padded X tile in LDS.
// Block = (Y, 16-ch chunk, b); thread (l, tc): 4 channels x 2x2 outputs.
__global__ __launch_bounds__(256) void carafe_kernel(
        const float* __restrict__ X, const float* __restrict__ ws,
        float* __restrict__ out) {
    const int H = 64, Wd = 64, C = 128, Ho = 128, Wo = 128, HW = H * Wd;
    int Y = blockIdx.x;
    int cchunk = blockIdx.y;
    int b = blockIdx.z;
    __shared__ float xs[16][5][68];
    int t = threadIdx.x;
    int c0 = cchunk * 16;
    const float* Xb = X + ((size_t)b * C + c0) * HW;
    for (int i = t; i < 16 * 5 * 68; i += 256) {
        int col = i % 68;
        int tmp = i / 68;
        int p = tmp % 5;
        int c = tmp / 5;
        int iy = Y + p - 2, ix = col - 2;
        float v = 0.f;
        if ((unsigned)iy < (unsigned)H && (unsigned)ix < (unsigned)Wd)
            v = Xb[(size_t)c * HW + iy * Wd + ix];
        xs[c][p][col] = v;
    }
    int l = t & 63;
    int tc = t >> 6;
    const float* wsrow = ws + (((size_t)b * 64 + Y) * 100) * 64 + l;
    float wreg[4][25];
#pragma unroll
    for (int rp = 0; rp < 4; ++rp)
#pragma unroll
        for (int j = 0; j < 25; ++j)
            wreg[rp][j] = wsrow[(rp * 25 + j) * 64];
    __syncthreads();

#pragma unroll
    for (int k = 0; k < 4; ++k) {
        int c = tc * 4 + k;
        float a00 = 0.f, a01 = 0.f, a10 = 0.f, a11 = 0.f;
#pragma unroll
        for (int p = 0; p < 5; ++p)
#pragma unroll
            for (int q = 0; q < 5; ++q) {
                float v = xs[c][p][l + q];
                int j = p * 5 + q;
                a00 = fmaf(wreg[0][j], v, a00);
                a01 = fmaf(wreg[1][j], v, a01);
                a10 = fmaf(wreg[2][j], v, a10);
                a11 = fmaf(wreg[3][j], v, a11);
            }
        size_t ob = (((size_t)b * C + (c0 + c)) * Ho + 2 * Y) * Wo + 2 * l;
        *reinterpret_cast<float2*>(&out[ob])      = make_float2(a00, a01);
        *reinterpret_cast<float2*>(&out[ob + Wo]) = make_float2(a10, a11);
    }
}

extern "C" void kernel_launch(void* const* d_in, const int* in_sizes, int n_in,
                              void* d_out, int out_size, void* d_ws, size_t ws_size,
                              hipStream_t stream) {
    const float* X          = (const float*)d_in[0];
    const float* comp_cv1_w = (const float*)d_in[1];
    const float* comp_cv1_s = (const float*)d_in[2];
    const float* comp_cv1_b = (const float*)d_in[3];
    const float* comp_dw3_w = (const float*)d_in[4];
    const float* comp_dw3_s = (const float*)d_in[5];
    const float* comp_dw3_b = (const float*)d_in[6];
    const float* comp_dw5_w = (const float*)d_in[7];
    const float* comp_dw5_s = (const float*)d_in[8];
    const float* comp_dw5_b = (const float*)d_in[9];
    const float* comp_px_w  = (const float*)d_in[10];
    const float* comp_px_s  = (const float*)d_in[11];
    const float* comp_px_b  = (const float*)d_in[12];
    const float* enc_cv1_w  = (const float*)d_in[13];
    const float* enc_cv1_s  = (const float*)d_in[14];
    const float* enc_cv1_b  = (const float*)d_in[15];
    const float* enc_dw3_w  = (const float*)d_in[16];
    const float* enc_dw3_s  = (const float*)d_in[17];
    const float* enc_dw3_b  = (const float*)d_in[18];
    const float* enc_dw5_w  = (const float*)d_in[19];
    const float* enc_dw5_s  = (const float*)d_in[20];
    const float* enc_dw5_b  = (const float*)d_in[21];
    const float* enc_px_w   = (const float*)d_in[22];
    const float* enc_px_s   = (const float*)d_in[23];
    const float* enc_px_b   = (const float*)d_in[24];
    float* out = (float*)d_out;

    const int B = 2, HW = 64 * 64;
    float* x1c = (float*)d_ws;                 // [B, 32, HW]
    float* x1e = x1c + (size_t)B * 32 * HW;    // [B, 50, HW]
    float* ws  = x1e + (size_t)B * 50 * HW;    // [B, 64, 4, 25, 64]

    int pixBlocks = (B * HW + 255) / 256;      // 32

    // comp cv1 (1x1, 128 -> 32)
    pw_conv_silu<4, 128><<<dim3(pixBlocks, 8), 256, 0, stream>>>(
        X, HW, B, comp_cv1_w, comp_cv1_s, comp_cv1_b, x1c, 32);

    // comp dw + comp px + enc cv1
    fusedA_kernel<<<dim3(64, B), 256, 0, stream>>>(
        x1c,
        comp_dw3_w, comp_dw3_s, comp_dw3_b,
        comp_dw5_w, comp_dw5_s, comp_dw5_b,
        comp_px_w, comp_px_s, comp_px_b,
        enc_cv1_w, enc_cv1_s, enc_cv1_b,
        x1e);

    // enc dw + enc px + softmax + pixel-shuffle transpose
    fusedB_kernel<<<dim3(64, B), 256, 0, stream>>>(
        x1e,
        enc_dw3_w, enc_dw3_s, enc_dw3_b,
        enc_dw5_w, enc_dw5_s, enc_dw5_b,
        enc_px_w, enc_px_s, enc_px_b,
        ws);

    // CARAFE reassembly
    carafe_kernel<<<dim3(64, 8, B), 256, 0, stream>>>(X, ws, out);
}

// Round 8
// 129.125 us; speedup vs baseline: 1.0845x; 1.0845x over previous
//
#include <hip/hip_runtime.h>
#include <math.h>

__device__ __forceinline__ float silu_act(float y) {
    return y / (1.f + __expf(-y));
}

// Pointwise 1x1 conv + scale/bias + SiLU. Compile-time Cin for full unroll.
template<int TC, int CIN>
__global__ void pw_conv_silu(const float* __restrict__ in, int HW, int B,
                             const float* __restrict__ w,
                             const float* __restrict__ sc, const float* __restrict__ bi,
                             float* __restrict__ out, int CoutStride) {
    int g = blockIdx.x * blockDim.x + threadIdx.x;
    if (g >= B * HW) return;
    int b = g / HW, pix = g - b * HW;
    int co0 = blockIdx.y * TC;
    float acc[TC];
#pragma unroll
    for (int j = 0; j < TC; ++j) acc[j] = 0.f;
    const float* ip = in + (size_t)b * CIN * HW + pix;
    const float* wp = w + (size_t)co0 * CIN;
#pragma unroll 8
    for (int ci = 0; ci < CIN; ++ci) {
        float v = ip[(size_t)ci * HW];
#pragma unroll
        for (int j = 0; j < TC; ++j)
            acc[j] = fmaf(v, wp[j * CIN + ci], acc[j]);
    }
#pragma unroll
    for (int j = 0; j < TC; ++j) {
        int co = co0 + j;
        float y = fmaf(acc[j], sc[co], bi[co]);
        out[((size_t)b * CoutStride + co) * HW + pix] = silu_act(y);
    }
}

// fusedA: comp dw3/dw5 + comp px (1x1) + enc cv1 (1x1).
// Block = (Y, column-quarter q, b): 16 pixels. 256 threads = (l = t&15, g = t>>4).
// In: x1c [b][32][4096]. Out: x1e [b][50][4096].
__global__ __launch_bounds__(256) void fusedA_kernel(
        const float* __restrict__ x1c,
        const float* __restrict__ w3, const float* __restrict__ s3, const float* __restrict__ b3,
        const float* __restrict__ w5, const float* __restrict__ s5, const float* __restrict__ b5,
        const float* __restrict__ pxw, const float* __restrict__ pxs, const float* __restrict__ pxb,
        const float* __restrict__ ew, const float* __restrict__ es, const float* __restrict__ eb,
        float* __restrict__ x1e) {
    const int H = 64, Wd = 64, HW = 4096;
    int Y = blockIdx.x, q = blockIdx.y, b = blockIdx.z;
    int x0 = q * 16;
    __shared__ float xs[32][5][20];   // rows Y-2..Y+2, cols x0-2..x0+17 (cc = ix-x0+2)
    __shared__ float cat[64][16];     // x1 (0..31), x2=dw (32..63)
    __shared__ float yrow[64][16];    // comp px output
    int t = threadIdx.x;
    const float* src = x1c + (size_t)b * 32 * HW;
    for (int i = t; i < 32 * 5 * 20; i += 256) {
        int cc = i % 20;
        int p = (i / 20) % 5;
        int c = i / 100;
        int iy = Y + p - 2, ix = x0 + cc - 2;
        float v = 0.f;
        if ((unsigned)iy < (unsigned)H && (unsigned)ix < (unsigned)Wd)
            v = src[(size_t)c * HW + iy * Wd + ix];
        xs[c][p][cc] = v;
    }
    __syncthreads();
    int l = t & 15;
    int g = t >> 4;
    // depthwise: c = k*16+g (k=0,1); c<16 -> k3 w3[c], else k5 w5[c-16]
#pragma unroll
    for (int k = 0; k < 2; ++k) {
        int c = k * 16 + g;
        float acc = 0.f, sc, bi;
        if (c < 16) {
            const float* wk = w3 + c * 9;
#pragma unroll
            for (int p = 0; p < 3; ++p)
#pragma unroll
                for (int kx = 0; kx < 3; ++kx)
                    acc = fmaf(xs[c][p + 1][l + kx + 1], wk[p * 3 + kx], acc);
            sc = s3[c]; bi = b3[c];
        } else {
            const float* wk = w5 + (c - 16) * 25;
#pragma unroll
            for (int p = 0; p < 5; ++p)
#pragma unroll
                for (int kx = 0; kx < 5; ++kx)
                    acc = fmaf(xs[c][p][l + kx], wk[p * 5 + kx], acc);
            sc = s5[c - 16]; bi = b5[c - 16];
        }
        cat[32 + c][l] = silu_act(fmaf(acc, sc, bi));
        cat[c][l] = xs[c][2][l + 2];
    }
    __syncthreads();
    // comp px: thread computes co = g*4 .. g*4+3
    {
        float acc[4] = {0.f, 0.f, 0.f, 0.f};
#pragma unroll 4
        for (int ci = 0; ci < 64; ++ci) {
            float xv = cat[ci][l];
#pragma unroll
            for (int k = 0; k < 4; ++k)
                acc[k] = fmaf(xv, pxw[(g * 4 + k) * 64 + ci], acc[k]);
        }
#pragma unroll
        for (int k = 0; k < 4; ++k) {
            int co = g * 4 + k;
            yrow[co][l] = silu_act(fmaf(acc[k], pxs[co], pxb[co]));
        }
    }
    __syncthreads();
    // enc cv1: thread computes ce = g + 16*j (j=0..3, ce<50)
    {
        float acc[4] = {0.f, 0.f, 0.f, 0.f};
#pragma unroll 4
        for (int co = 0; co < 64; ++co) {
            float yv = yrow[co][l];
#pragma unroll
            for (int j = 0; j < 4; ++j) {
                int ce = g + 16 * j;
                if (ce < 50)
                    acc[j] = fmaf(yv, ew[ce * 64 + co], acc[j]);
            }
        }
        float* dst = x1e + (size_t)b * 50 * HW + Y * Wd + x0 + l;
#pragma unroll
        for (int j = 0; j < 4; ++j) {
            int ce = g + 16 * j;
            if (ce < 50)
                dst[(size_t)ce * HW] = silu_act(fmaf(acc[j], es[ce], eb[ce]));
        }
    }
}

// fusedB: enc dw3/dw5 + enc px (1x1). Writes RAW weights wraw [b][100][4096]
// (softmax stays fused in carafe). Block = (Y, q, b); thread (l = t&15, g = t>>4).
__global__ __launch_bounds__(256) void fusedB_kernel(
        const float* __restrict__ x1e,
        const float* __restrict__ w3, const float* __restrict__ s3, const float* __restrict__ b3,
        const float* __restrict__ w5, const float* __restrict__ s5, const float* __restrict__ b5,
        const float* __restrict__ pxw, const float* __restrict__ pxs, const float* __restrict__ pxb,
        float* __restrict__ wraw) {
    const int H = 64, Wd = 64, HW = 4096;
    int Y = blockIdx.x, q = blockIdx.y, b = blockIdx.z;
    int x0 = q * 16;
    __shared__ float xs[50][5][20];
    __shared__ float cat[100][16];
    int t = threadIdx.x;
    const float* src = x1e + (size_t)b * 50 * HW;
    for (int i = t; i < 50 * 5 * 20; i += 256) {
        int cc = i % 20;
        int p = (i / 20) % 5;
        int c = i / 100;
        int iy = Y + p - 2, ix = x0 + cc - 2;
        float v = 0.f;
        if ((unsigned)iy < (unsigned)H && (unsigned)ix < (unsigned)Wd)
            v = src[(size_t)c * HW + iy * Wd + ix];
        xs[c][p][cc] = v;
    }
    __syncthreads();
    int l = t & 15;
    int g = t >> 4;
    // depthwise: c = k*16+g (k=0..3, c<50); c<25 -> k3 w3[c], else k5 w5[c-25]
#pragma unroll
    for (int k = 0; k < 4; ++k) {
        int c = k * 16 + g;
        if (c < 50) {
            float acc = 0.f, sc, bi;
            if (c < 25) {
                const float* wk = w3 + c * 9;
#pragma unroll
                for (int p = 0; p < 3; ++p)
#pragma unroll
                    for (int kx = 0; kx < 3; ++kx)
                        acc = fmaf(xs[c][p + 1][l + kx + 1], wk[p * 3 + kx], acc);
                sc = s3[c]; bi = b3[c];
            } else {
                const float* wk = w5 + (c - 25) * 25;
#pragma unroll
                for (int p = 0; p < 5; ++p)
#pragma unroll
                    for (int kx = 0; kx < 5; ++kx)
                        acc = fmaf(xs[c][p][l + kx], wk[p * 5 + kx], acc);
                sc = s5[c - 25]; bi = b5[c - 25];
            }
            cat[50 + c][l] = silu_act(fmaf(acc, sc, bi));
            cat[c][l] = xs[c][2][l + 2];
        }
    }
    __syncthreads();
    // enc px: thread computes co = g + 16*j (j=0..6, co<100)
    float acc[7] = {0.f, 0.f, 0.f, 0.f, 0.f, 0.f, 0.f};
#pragma unroll 4
    for (int ci = 0; ci < 100; ++ci) {
        float xv = cat[ci][l];
#pragma unroll
        for (int j = 0; j < 7; ++j) {
            int co = g + 16 * j;
            if (co < 100)
                acc[j] = fmaf(xv, pxw[co * 100 + ci], acc[j]);
        }
    }
    float* dst = wraw + (size_t)b * 100 * HW + Y * Wd + x0 + l;
#pragma unroll
    for (int j = 0; j < 7; ++j) {
        int co = g + 16 * j;
        if (co < 100)
            dst[(size_t)co * HW] = silu_act(fmaf(acc[j], pxs[co], pxb[co]));
    }
}

// CARAFE v4 (round-6-proven): zero-padded X tile in LDS; raw weights loaded
// coalesced and softmaxed IN REGISTERS. Block = (Y, 16-ch chunk, b);
// thread (l = t&63, tc = t>>6): 4 channels x 2x2 outputs.
__global__ __launch_bounds__(256) void carafe_kernel(
        const float* __restrict__ X, const float* __restrict__ wraw,
        float* __restrict__ out) {
    const int H = 64, Wd = 64, C = 128, Ho = 128, Wo = 128, HW = H * Wd;
    int Y = blockIdx.x;
    int cchunk = blockIdx.y;
    int b = blockIdx.z;
    __shared__ float xs[16][5][68];
    int t = threadIdx.x;
    int c0 = cchunk * 16;
    const float* Xb = X + ((size_t)b * C + c0) * HW;
    for (int i = t; i < 16 * 5 * 68; i += 256) {
        int col = i % 68;
        int tmp = i / 68;
        int p = tmp % 5;
        int c = tmp / 5;
        int iy = Y + p - 2, ix = col - 2;
        float v = 0.f;
        if ((unsigned)iy < (unsigned)H && (unsigned)ix < (unsigned)Wd)
            v = Xb[(size_t)c * HW + iy * Wd + ix];
        xs[c][p][col] = v;
    }
    int l = t & 63;
    int tc = t >> 6;
    const float* wb = wraw + (size_t)b * 100 * HW + Y * Wd + l;
    float wreg[4][25];
#pragma unroll
    for (int rp = 0; rp < 4; ++rp)
#pragma unroll
        for (int j = 0; j < 25; ++j)
            wreg[rp][j] = wb[(size_t)(j * 4 + rp) * HW];
#pragma unroll
    for (int rp = 0; rp < 4; ++rp) {
        float m = -1e30f;
#pragma unroll
        for (int j = 0; j < 25; ++j) m = fmaxf(m, wreg[rp][j]);
        float s = 0.f;
#pragma unroll
        for (int j = 0; j < 25; ++j) { wreg[rp][j] = __expf(wreg[rp][j] - m); s += wreg[rp][j]; }
        float inv = 1.f / s;
#pragma unroll
        for (int j = 0; j < 25; ++j) wreg[rp][j] *= inv;
    }
    __syncthreads();

#pragma unroll
    for (int k = 0; k < 4; ++k) {
        int c = tc * 4 + k;
        float a00 = 0.f, a01 = 0.f, a10 = 0.f, a11 = 0.f;
#pragma unroll
        for (int p = 0; p < 5; ++p)
#pragma unroll
            for (int q = 0; q < 5; ++q) {
                float v = xs[c][p][l + q];
                int j = p * 5 + q;
                a00 = fmaf(wreg[0][j], v, a00);
                a01 = fmaf(wreg[1][j], v, a01);
                a10 = fmaf(wreg[2][j], v, a10);
                a11 = fmaf(wreg[3][j], v, a11);
            }
        size_t ob = (((size_t)b * C + (c0 + c)) * Ho + 2 * Y) * Wo + 2 * l;
        *reinterpret_cast<float2*>(&out[ob])      = make_float2(a00, a01);
        *reinterpret_cast<float2*>(&out[ob + Wo]) = make_float2(a10, a11);
    }
}

extern "C" void kernel_launch(void* const* d_in, const int* in_sizes, int n_in,
                              void* d_out, int out_size, void* d_ws, size_t ws_size,
                              hipStream_t stream) {
    const float* X          = (const float*)d_in[0];
    const float* comp_cv1_w = (const float*)d_in[1];
    const float* comp_cv1_s = (const float*)d_in[2];
    const float* comp_cv1_b = (const float*)d_in[3];
    const float* comp_dw3_w = (const float*)d_in[4];
    const float* comp_dw3_s = (const float*)d_in[5];
    const float* comp_dw3_b = (const float*)d_in[6];
    const float* comp_dw5_w = (const float*)d_in[7];
    const float* comp_dw5_s = (const float*)d_in[8];
    const float* comp_dw5_b = (const float*)d_in[9];
    const float* comp_px_w  = (const float*)d_in[10];
    const float* comp_px_s  = (const float*)d_in[11];
    const float* comp_px_b  = (const float*)d_in[12];
    const float* enc_cv1_w  = (const float*)d_in[13];
    const float* enc_cv1_s  = (const float*)d_in[14];
    const float* enc_cv1_b  = (const float*)d_in[15];
    const float* enc_dw3_w  = (const float*)d_in[16];
    const float* enc_dw3_s  = (const float*)d_in[17];
    const float* enc_dw3_b  = (const float*)d_in[18];
    const float* enc_dw5_w  = (const float*)d_in[19];
    const float* enc_dw5_s  = (const float*)d_in[20];
    const float* enc_dw5_b  = (const float*)d_in[21];
    const float* enc_px_w   = (const float*)d_in[22];
    const float* enc_px_s   = (const float*)d_in[23];
    const float* enc_px_b   = (const float*)d_in[24];
    float* out = (float*)d_out;

    const int B = 2, HW = 64 * 64;
    float* x1c  = (float*)d_ws;                  // [B, 32, HW]
    float* x1e  = x1c  + (size_t)B * 32 * HW;    // [B, 50, HW]
    float* wraw = x1e  + (size_t)B * 50 * HW;    // [B, 100, HW]

    // comp cv1 (1x1, 128 -> 32), 512 blocks
    pw_conv_silu<2, 128><<<dim3(32, 16), 256, 0, stream>>>(
        X, HW, B, comp_cv1_w, comp_cv1_s, comp_cv1_b, x1c, 32);

    // comp dw + comp px + enc cv1, 512 blocks
    fusedA_kernel<<<dim3(64, 4, B), 256, 0, stream>>>(
        x1c,
        comp_dw3_w, comp_dw3_s, comp_dw3_b,
        comp_dw5_w, comp_dw5_s, comp_dw5_b,
        comp_px_w, comp_px_s, comp_px_b,
        enc_cv1_w, enc_cv1_s, enc_cv1_b,
        x1e);

    // enc dw + enc px (raw weights), 512 blocks
    fusedB_kernel<<<dim3(64, 4, B), 256, 0, stream>>>(
        x1e,
        enc_dw3_w, enc_dw3_s, enc_dw3_b,
        enc_dw5_w, enc_dw5_s, enc_dw5_b,
        enc_px_w, enc_px_s, enc_px_b,
        wraw);

    // CARAFE reassembly (softmax fused, in-register), 1024 blocks
    carafe_kernel<<<dim3(64, 8, B), 256, 0, stream>>>(X, wraw, out);
}

// Round 9
// 125.930 us; speedup vs baseline: 1.1120x; 1.0254x over previous
//
#include <hip/hip_runtime.h>
#include <math.h>

__device__ __forceinline__ float silu_act(float y) {
    return y / (1.f + __expf(-y));
}

// Pointwise 1x1 conv + scale/bias + SiLU. Compile-time Cin for full unroll.
// Weight index depends only on blockIdx.y -> wave-uniform -> SGPR loads.
template<int TC, int CIN>
__global__ void pw_conv_silu(const float* __restrict__ in, int HW, int B,
                             const float* __restrict__ w,
                             const float* __restrict__ sc, const float* __restrict__ bi,
                             float* __restrict__ out, int CoutStride) {
    int g = blockIdx.x * blockDim.x + threadIdx.x;
    if (g >= B * HW) return;
    int b = g / HW, pix = g - b * HW;
    int co0 = blockIdx.y * TC;
    float acc[TC];
#pragma unroll
    for (int j = 0; j < TC; ++j) acc[j] = 0.f;
    const float* ip = in + (size_t)b * CIN * HW + pix;
    const float* wp = w + (size_t)co0 * CIN;
#pragma unroll 8
    for (int ci = 0; ci < CIN; ++ci) {
        float v = ip[(size_t)ci * HW];
#pragma unroll
        for (int j = 0; j < TC; ++j)
            acc[j] = fmaf(v, wp[j * CIN + ci], acc[j]);
    }
#pragma unroll
    for (int j = 0; j < TC; ++j) {
        int co = co0 + j;
        float y = fmaf(acc[j], sc[co], bi[co]);
        out[((size_t)b * CoutStride + co) * HW + pix] = silu_act(y);
    }
}

// fusedA: comp dw3/dw5 + comp px (1x1).
// Block = (Y, og, b), 256 thr = (l = t&63 pixel, w = t>>6 wave).
// dw replicated across the 4 og-blocks (cheap); px outputs co = og*16+w*4+k
// with wave-uniform weights. In: x1c [b][32][4096]; out: y [b][64][4096].
__global__ __launch_bounds__(256) void fusedA_kernel(
        const float* __restrict__ x1c,
        const float* __restrict__ w3, const float* __restrict__ s3, const float* __restrict__ b3,
        const float* __restrict__ w5, const float* __restrict__ s5, const float* __restrict__ b5,
        const float* __restrict__ pxw, const float* __restrict__ pxs, const float* __restrict__ pxb,
        float* __restrict__ y) {
    const int H = 64, Wd = 64, HW = 4096;
    int Y = blockIdx.x, og = blockIdx.y, b = blockIdx.z;
    __shared__ float cat[64][64];     // x1 (0..31), x2=dw (32..63)
    int t = threadIdx.x;
    int l = t & 63;
    int w = __builtin_amdgcn_readfirstlane(t >> 6);
    const float* src = x1c + (size_t)b * 32 * HW;
    // depthwise from global (coalesced over l), wave w: c = w + 4k
#pragma unroll
    for (int k = 0; k < 8; ++k) {
        int c = w + 4 * k;
        const float* ip = src + (size_t)c * HW;
        float acc = 0.f, sc, bi;
        if (c < 16) {
            const float* wk = w3 + c * 9;
#pragma unroll
            for (int p = 0; p < 3; ++p) {
                int iy = Y + p - 1;
                if ((unsigned)iy >= (unsigned)H) continue;
#pragma unroll
                for (int kx = 0; kx < 3; ++kx) {
                    int ix = l + kx - 1;
                    if ((unsigned)ix >= (unsigned)Wd) continue;
                    acc = fmaf(ip[iy * Wd + ix], wk[p * 3 + kx], acc);
                }
            }
            sc = s3[c]; bi = b3[c];
        } else {
            const float* wk = w5 + (c - 16) * 25;
#pragma unroll
            for (int p = 0; p < 5; ++p) {
                int iy = Y + p - 2;
                if ((unsigned)iy >= (unsigned)H) continue;
#pragma unroll
                for (int kx = 0; kx < 5; ++kx) {
                    int ix = l + kx - 2;
                    if ((unsigned)ix >= (unsigned)Wd) continue;
                    acc = fmaf(ip[iy * Wd + ix], wk[p * 5 + kx], acc);
                }
            }
            sc = s5[c - 16]; bi = b5[c - 16];
        }
        cat[c][l] = ip[Y * Wd + l];
        cat[32 + c][l] = silu_act(fmaf(acc, sc, bi));
    }
    __syncthreads();
    // px: wave w computes co = og*16 + w*4 + {0..3}; weights wave-uniform
    {
        int co0 = og * 16 + w * 4;
        const float* wp = pxw + (size_t)co0 * 64;
        float acc[4] = {0.f, 0.f, 0.f, 0.f};
#pragma unroll 8
        for (int ci = 0; ci < 64; ++ci) {
            float xv = cat[ci][l];
#pragma unroll
            for (int k = 0; k < 4; ++k)
                acc[k] = fmaf(xv, wp[k * 64 + ci], acc[k]);
        }
#pragma unroll
        for (int k = 0; k < 4; ++k) {
            int co = co0 + k;
            y[((size_t)b * 64 + co) * HW + Y * Wd + l] =
                silu_act(fmaf(acc[k], pxs[co], pxb[co]));
        }
    }
}

// fusedB: enc dw3/dw5 + enc px (1x1) + softmax + pixel-shuffle transpose.
// Block = (Y, rp, b), 256 thr = (l = t&63, w = t>>6). dw replicated across
// the 4 rp-blocks. px outputs co = j*4+rp, j = w+4*jj (wave-uniform weights).
// Softmax over j done by wave 0 via LDS; writes ws[b][Y][rp][j][l].
__global__ __launch_bounds__(256) void fusedB_kernel(
        const float* __restrict__ x1e,
        const float* __restrict__ w3, const float* __restrict__ s3, const float* __restrict__ b3,
        const float* __restrict__ w5, const float* __restrict__ s5, const float* __restrict__ b5,
        const float* __restrict__ pxw, const float* __restrict__ pxs, const float* __restrict__ pxb,
        float* __restrict__ ws) {
    const int H = 64, Wd = 64, HW = 4096;
    int Y = blockIdx.x, rp = blockIdx.y, b = blockIdx.z;
    __shared__ float cat[100][64];    // x1e (0..49), x2e=dw (50..99)
    __shared__ float pbuf[25][64];
    int t = threadIdx.x;
    int l = t & 63;
    int w = __builtin_amdgcn_readfirstlane(t >> 6);
    const float* src = x1e + (size_t)b * 50 * HW;
    // depthwise from global, wave w: c = w + 4k (c < 50)
#pragma unroll
    for (int k = 0; k < 13; ++k) {
        int c = w + 4 * k;
        if (c < 50) {
            const float* ip = src + (size_t)c * HW;
            float acc = 0.f, sc, bi;
            if (c < 25) {
                const float* wk = w3 + c * 9;
#pragma unroll
                for (int p = 0; p < 3; ++p) {
                    int iy = Y + p - 1;
                    if ((unsigned)iy >= (unsigned)H) continue;
#pragma unroll
                    for (int kx = 0; kx < 3; ++kx) {
                        int ix = l + kx - 1;
                        if ((unsigned)ix >= (unsigned)Wd) continue;
                        acc = fmaf(ip[iy * Wd + ix], wk[p * 3 + kx], acc);
                    }
                }
                sc = s3[c]; bi = b3[c];
            } else {
                const float* wk = w5 + (c - 25) * 25;
#pragma unroll
                for (int p = 0; p < 5; ++p) {
                    int iy = Y + p - 2;
                    if ((unsigned)iy >= (unsigned)H) continue;
#pragma unroll
                    for (int kx = 0; kx < 5; ++kx) {
                        int ix = l + kx - 2;
                        if ((unsigned)ix >= (unsigned)Wd) continue;
                        acc = fmaf(ip[iy * Wd + ix], wk[p * 5 + kx], acc);
                    }
                }
                sc = s5[c - 25]; bi = b5[c - 25];
            }
            cat[c][l] = ip[Y * Wd + l];
            cat[50 + c][l] = silu_act(fmaf(acc, sc, bi));
        }
    }
    __syncthreads();
    // px: wave w computes j = w + 4*jj (j < 25), co = j*4 + rp
    {
        float acc[7] = {0.f, 0.f, 0.f, 0.f, 0.f, 0.f, 0.f};
#pragma unroll 4
        for (int ci = 0; ci < 100; ++ci) {
            float xv = cat[ci][l];
#pragma unroll
            for (int jj = 0; jj < 7; ++jj) {
                int j = w + 4 * jj;
                if (j < 25)
                    acc[jj] = fmaf(xv, pxw[(size_t)(j * 4 + rp) * 100 + ci], acc[jj]);
            }
        }
#pragma unroll
        for (int jj = 0; jj < 7; ++jj) {
            int j = w + 4 * jj;
            if (j < 25) {
                int co = j * 4 + rp;
                pbuf[j][l] = silu_act(fmaf(acc[jj], pxs[co], pxb[co]));
            }
        }
    }
    __syncthreads();
    // softmax over the 25 taps (wave 0), write pre-normalized weights
    if (t < 64) {
        float v[25];
        float m = -1e30f;
#pragma unroll
        for (int j = 0; j < 25; ++j) { v[j] = pbuf[j][l]; m = fmaxf(m, v[j]); }
        float s = 0.f;
#pragma unroll
        for (int j = 0; j < 25; ++j) { v[j] = __expf(v[j] - m); s += v[j]; }
        float inv = 1.f / s;
        float* dst = ws + ((((size_t)b * 64 + Y) * 4 + rp) * 25) * 64 + l;
#pragma unroll
        for (int j = 0; j < 25; ++j) dst[j * 64] = v[j] * inv;
    }
}

// CARAFE v5: pre-softmaxed weights from ws (coalesced), zero-padded X tile
// in LDS. Block = (Y, 16-ch chunk, b); thread (l, tc): 4 ch x 2x2 outputs.
__global__ __launch_bounds__(256) void carafe_kernel(
        const float* __restrict__ X, const float* __restrict__ ws,
        float* __restrict__ out) {
    const int H = 64, Wd = 64, C = 128, Ho = 128, Wo = 128, HW = H * Wd;
    int Y = blockIdx.x;
    int cchunk = blockIdx.y;
    int b = blockIdx.z;
    __shared__ float xs[16][5][68];
    int t = threadIdx.x;
    int c0 = cchunk * 16;
    const float* Xb = X + ((size_t)b * C + c0) * HW;
    for (int i = t; i < 16 * 5 * 68; i += 256) {
        int col = i % 68;
        int tmp = i / 68;
        int p = tmp % 5;
        int c = tmp / 5;
        int iy = Y + p - 2, ix = col - 2;
        float v = 0.f;
        if ((unsigned)iy < (unsigned)H && (unsigned)ix < (unsigned)Wd)
            v = Xb[(size_t)c * HW + iy * Wd + ix];
        xs[c][p][col] = v;
    }
    int l = t & 63;
    int tc = t >> 6;
    const float* wsrow = ws + (((size_t)b * 64 + Y) * 100) * 64 + l;
    float wreg[4][25];
#pragma unroll
    for (int rp = 0; rp < 4; ++rp)
#pragma unroll
        for (int j = 0; j < 25; ++j)
            wreg[rp][j] = wsrow[(rp * 25 + j) * 64];
    __syncthreads();

#pragma unroll
    for (int k = 0; k < 4; ++k) {
        int c = tc * 4 + k;
        float a00 = 0.f, a01 = 0.f, a10 = 0.f, a11 = 0.f;
#pragma unroll
        for (int p = 0; p < 5; ++p)
#pragma unroll
            for (int q = 0; q < 5; ++q) {
                float v = xs[c][p][l + q];
                int j = p * 5 + q;
                a00 = fmaf(wreg[0][j], v, a00);
                a01 = fmaf(wreg[1][j], v, a01);
                a10 = fmaf(wreg[2][j], v, a10);
                a11 = fmaf(wreg[3][j], v, a11);
            }
        size_t ob = (((size_t)b * C + (c0 + c)) * Ho + 2 * Y) * Wo + 2 * l;
        *reinterpret_cast<float2*>(&out[ob])      = make_float2(a00, a01);
        *reinterpret_cast<float2*>(&out[ob + Wo]) = make_float2(a10, a11);
    }
}

extern "C" void kernel_launch(void* const* d_in, const int* in_sizes, int n_in,
                              void* d_out, int out_size, void* d_ws, size_t ws_size,
                              hipStream_t stream) {
    const float* X          = (const float*)d_in[0];
    const float* comp_cv1_w = (const float*)d_in[1];
    const float* comp_cv1_s = (const float*)d_in[2];
    const float* comp_cv1_b = (const float*)d_in[3];
    const float* comp_dw3_w = (const float*)d_in[4];
    const float* comp_dw3_s = (const float*)d_in[5];
    const float* comp_dw3_b = (const float*)d_in[6];
    const float* comp_dw5_w = (const float*)d_in[7];
    const float* comp_dw5_s = (const float*)d_in[8];
    const float* comp_dw5_b = (const float*)d_in[9];
    const float* comp_px_w  = (const float*)d_in[10];
    const float* comp_px_s  = (const float*)d_in[11];
    const float* comp_px_b  = (const float*)d_in[12];
    const float* enc_cv1_w  = (const float*)d_in[13];
    const float* enc_cv1_s  = (const float*)d_in[14];
    const float* enc_cv1_b  = (const float*)d_in[15];
    const float* enc_dw3_w  = (const float*)d_in[16];
    const float* enc_dw3_s  = (const float*)d_in[17];
    const float* enc_dw3_b  = (const float*)d_in[18];
    const float* enc_dw5_w  = (const float*)d_in[19];
    const float* enc_dw5_s  = (const float*)d_in[20];
    const float* enc_dw5_b  = (const float*)d_in[21];
    const float* enc_px_w   = (const float*)d_in[22];
    const float* enc_px_s   = (const float*)d_in[23];
    const float* enc_px_b   = (const float*)d_in[24];
    float* out = (float*)d_out;

    const int B = 2, HW = 64 * 64;
    float* x1c = (float*)d_ws;                 // [B, 32, HW]
    float* yc  = x1c + (size_t)B * 32 * HW;    // [B, 64, HW]
    float* x1e = yc  + (size_t)B * 64 * HW;    // [B, 50, HW]
    float* ws  = x1e + (size_t)B * 50 * HW;    // [B, 64, 4, 25, 64]

    // comp cv1 (1x1, 128 -> 32)
    pw_conv_silu<4, 128><<<dim3(32, 8), 256, 0, stream>>>(
        X, HW, B, comp_cv1_w, comp_cv1_s, comp_cv1_b, x1c, 32);

    // comp dw + comp px, 512 blocks
    fusedA_kernel<<<dim3(64, 4, B), 256, 0, stream>>>(
        x1c,
        comp_dw3_w, comp_dw3_s, comp_dw3_b,
        comp_dw5_w, comp_dw5_s, comp_dw5_b,
        comp_px_w, comp_px_s, comp_px_b,
        yc);

    // enc cv1 (1x1, 64 -> 50)
    pw_conv_silu<5, 64><<<dim3(32, 10), 256, 0, stream>>>(
        yc, HW, B, enc_cv1_w, enc_cv1_s, enc_cv1_b, x1e, 50);

    // enc dw + enc px + softmax, 512 blocks
    fusedB_kernel<<<dim3(64, 4, B), 256, 0, stream>>>(
        x1e,
        enc_dw3_w, enc_dw3_s, enc_dw3_b,
        enc_dw5_w, enc_dw5_s, enc_dw5_b,
        enc_px_w, enc_px_s, enc_px_b,
        ws);

    // CARAFE reassembly (weights pre-softmaxed), 1024 blocks
    carafe_kernel<<<dim3(64, 8, B), 256, 0, stream>>>(X, ws, out);
}

// Round 10
// 92.256 us; speedup vs baseline: 1.5179x; 1.3650x over previous
//
#include <hip/hip_runtime.h>
#include <math.h>

__device__ __forceinline__ float silu_act(float y) {
    return y / (1.f + __expf(-y));
}

// Pointwise 1x1 conv + scale/bias + SiLU. Compile-time Cin for full unroll.
// Weight rows block-uniform -> SGPR loads; lane = pixel -> coalesced.
template<int TC, int CIN>
__global__ void pw_conv_silu(const float* __restrict__ in, int HW, int B,
                             const float* __restrict__ w,
                             const float* __restrict__ sc, const float* __restrict__ bi,
                             float* __restrict__ out, int CoutStride) {
    int g = blockIdx.x * blockDim.x + threadIdx.x;
    if (g >= B * HW) return;
    int b = g / HW, pix = g - b * HW;
    int co0 = blockIdx.y * TC;
    float acc[TC];
#pragma unroll
    for (int j = 0; j < TC; ++j) acc[j] = 0.f;
    const float* ip = in + (size_t)b * CIN * HW + pix;
    const float* wp = w + (size_t)co0 * CIN;
#pragma unroll 8
    for (int ci = 0; ci < CIN; ++ci) {
        float v = ip[(size_t)ci * HW];
#pragma unroll
        for (int j = 0; j < TC; ++j)
            acc[j] = fmaf(v, wp[j * CIN + ci], acc[j]);
    }
#pragma unroll
    for (int j = 0; j < TC; ++j) {
        int co = co0 + j;
        float y = fmaf(acc[j], sc[co], bi[co]);
        out[((size_t)b * CoutStride + co) * HW + pix] = silu_act(y);
    }
}

// Fused depthwise 3x3 (channels [0,ch)) and 5x5 (channels [ch,2ch)) + SiLU.
// Pixel-channel-parallel, 1600 blocks for the enc stage: latency hidden by TLP.
__global__ void dw_conv_silu(float* __restrict__ cat, int ch, int H, int W, int Ctot, int B,
                             const float* __restrict__ w3, const float* __restrict__ s3,
                             const float* __restrict__ b3,
                             const float* __restrict__ w5, const float* __restrict__ s5,
                             const float* __restrict__ b5) {
    int HW = H * W;
    int idx = blockIdx.x * blockDim.x + threadIdx.x;
    int total = B * 2 * ch * HW;
    if (idx >= total) return;
    int pix = idx % HW;
    int t = idx / HW;
    int c2 = t % (2 * ch);
    int b = t / (2 * ch);
    int x = pix % W, y = pix / W;
    const float* ip = cat + ((size_t)b * Ctot + c2) * HW;
    float acc = 0.f, scale, bias;
    if (c2 < ch) {
        const float* wk = w3 + c2 * 9;
#pragma unroll
        for (int ky = 0; ky < 3; ++ky) {
            int iy = y + ky - 1;
            if ((unsigned)iy >= (unsigned)H) continue;
#pragma unroll
            for (int kx = 0; kx < 3; ++kx) {
                int ix = x + kx - 1;
                if ((unsigned)ix >= (unsigned)W) continue;
                acc = fmaf(ip[iy * W + ix], wk[ky * 3 + kx], acc);
            }
        }
        scale = s3[c2]; bias = b3[c2];
    } else {
        int c = c2 - ch;
        const float* wk = w5 + c * 25;
#pragma unroll
        for (int ky = 0; ky < 5; ++ky) {
            int iy = y + ky - 2;
            if ((unsigned)iy >= (unsigned)H) continue;
#pragma unroll
            for (int kx = 0; kx < 5; ++kx) {
                int ix = x + kx - 2;
                if ((unsigned)ix >= (unsigned)W) continue;
                acc = fmaf(ip[iy * W + ix], wk[ky * 5 + kx], acc);
            }
        }
        scale = s5[c]; bias = b5[c];
    }
    float v = fmaf(acc, scale, bias);
    cat[((size_t)b * Ctot + 2 * ch + c2) * HW + pix] = silu_act(v);
}

// fusedA (round-9-proven, ~7 us): comp dw3/dw5 + comp px (1x1).
// Block = (Y, og, b), 256 thr = (l = t&63 pixel, w = t>>6 wave).
// dw replicated across the 4 og-blocks (cheap); px outputs co = og*16+w*4+k
// with wave-uniform weights (1 KB/wave). In: x1c [b][32][HW]; out: y [b][64][HW].
__global__ __launch_bounds__(256) void fusedA_kernel(
        const float* __restrict__ x1c,
        const float* __restrict__ w3, const float* __restrict__ s3, const float* __restrict__ b3,
        const float* __restrict__ w5, const float* __restrict__ s5, const float* __restrict__ b5,
        const float* __restrict__ pxw, const float* __restrict__ pxs, const float* __restrict__ pxb,
        float* __restrict__ y) {
    const int H = 64, Wd = 64, HW = 4096;
    int Y = blockIdx.x, og = blockIdx.y, b = blockIdx.z;
    __shared__ float cat[64][64];     // x1 (0..31), x2=dw (32..63)
    int t = threadIdx.x;
    int l = t & 63;
    int w = __builtin_amdgcn_readfirstlane(t >> 6);
    const float* src = x1c + (size_t)b * 32 * HW;
#pragma unroll
    for (int k = 0; k < 8; ++k) {
        int c = w + 4 * k;
        const float* ip = src + (size_t)c * HW;
        float acc = 0.f, sc, bi;
        if (c < 16) {
            const float* wk = w3 + c * 9;
#pragma unroll
            for (int p = 0; p < 3; ++p) {
                int iy = Y + p - 1;
                if ((unsigned)iy >= (unsigned)H) continue;
#pragma unroll
                for (int kx = 0; kx < 3; ++kx) {
                    int ix = l + kx - 1;
                    if ((unsigned)ix >= (unsigned)Wd) continue;
                    acc = fmaf(ip[iy * Wd + ix], wk[p * 3 + kx], acc);
                }
            }
            sc = s3[c]; bi = b3[c];
        } else {
            const float* wk = w5 + (c - 16) * 25;
#pragma unroll
            for (int p = 0; p < 5; ++p) {
                int iy = Y + p - 2;
                if ((unsigned)iy >= (unsigned)H) continue;
#pragma unroll
                for (int kx = 0; kx < 5; ++kx) {
                    int ix = l + kx - 2;
                    if ((unsigned)ix >= (unsigned)Wd) continue;
                    acc = fmaf(ip[iy * Wd + ix], wk[p * 5 + kx], acc);
                }
            }
            sc = s5[c - 16]; bi = b5[c - 16];
        }
        cat[c][l] = ip[Y * Wd + l];
        cat[32 + c][l] = silu_act(fmaf(acc, sc, bi));
    }
    __syncthreads();
    {
        int co0 = og * 16 + w * 4;
        const float* wp = pxw + (size_t)co0 * 64;
        float acc[4] = {0.f, 0.f, 0.f, 0.f};
#pragma unroll 8
        for (int ci = 0; ci < 64; ++ci) {
            float xv = cat[ci][l];
#pragma unroll
            for (int k = 0; k < 4; ++k)
                acc[k] = fmaf(xv, wp[k * 64 + ci], acc[k]);
        }
#pragma unroll
        for (int k = 0; k < 4; ++k) {
            int co = co0 + k;
            y[((size_t)b * 64 + co) * HW + Y * Wd + l] =
                silu_act(fmaf(acc[k], pxs[co], pxb[co]));
        }
    }
}

// CARAFE v4 (round-6-proven): zero-padded X tile in LDS; raw weights loaded
// coalesced and softmaxed IN REGISTERS. Block = (Y, 16-ch chunk, b);
// thread (l = t&63, tc = t>>6): 4 channels x 2x2 outputs.
__global__ __launch_bounds__(256) void carafe_kernel(
        const float* __restrict__ X, const float* __restrict__ wraw,
        float* __restrict__ out) {
    const int H = 64, Wd = 64, C = 128, Ho = 128, Wo = 128, HW = H * Wd;
    int Y = blockIdx.x;
    int cchunk = blockIdx.y;
    int b = blockIdx.z;
    __shared__ float xs[16][5][68];
    int t = threadIdx.x;
    int c0 = cchunk * 16;
    const float* Xb = X + ((size_t)b * C + c0) * HW;
    for (int i = t; i < 16 * 5 * 68; i += 256) {
        int col = i % 68;
        int tmp = i / 68;
        int p = tmp % 5;
        int c = tmp / 5;
        int iy = Y + p - 2, ix = col - 2;
        float v = 0.f;
        if ((unsigned)iy < (unsigned)H && (unsigned)ix < (unsigned)Wd)
            v = Xb[(size_t)c * HW + iy * Wd + ix];
        xs[c][p][col] = v;
    }
    int l = t & 63;
    int tc = t >> 6;
    const float* wb = wraw + (size_t)b * 100 * HW + Y * Wd + l;
    float wreg[4][25];
#pragma unroll
    for (int rp = 0; rp < 4; ++rp)
#pragma unroll
        for (int j = 0; j < 25; ++j)
            wreg[rp][j] = wb[(size_t)(j * 4 + rp) * HW];
#pragma unroll
    for (int rp = 0; rp < 4; ++rp) {
        float m = -1e30f;
#pragma unroll
        for (int j = 0; j < 25; ++j) m = fmaxf(m, wreg[rp][j]);
        float s = 0.f;
#pragma unroll
        for (int j = 0; j < 25; ++j) { wreg[rp][j] = __expf(wreg[rp][j] - m); s += wreg[rp][j]; }
        float inv = 1.f / s;
#pragma unroll
        for (int j = 0; j < 25; ++j) wreg[rp][j] *= inv;
    }
    __syncthreads();

#pragma unroll
    for (int k = 0; k < 4; ++k) {
        int c = tc * 4 + k;
        float a00 = 0.f, a01 = 0.f, a10 = 0.f, a11 = 0.f;
#pragma unroll
        for (int p = 0; p < 5; ++p)
#pragma unroll
            for (int q = 0; q < 5; ++q) {
                float v = xs[c][p][l + q];
                int j = p * 5 + q;
                a00 = fmaf(wreg[0][j], v, a00);
                a01 = fmaf(wreg[1][j], v, a01);
                a10 = fmaf(wreg[2][j], v, a10);
                a11 = fmaf(wreg[3][j], v, a11);
            }
        size_t ob = (((size_t)b * C + (c0 + c)) * Ho + 2 * Y) * Wo + 2 * l;
        *reinterpret_cast<float2*>(&out[ob])      = make_float2(a00, a01);
        *reinterpret_cast<float2*>(&out[ob + Wo]) = make_float2(a10, a11);
    }
}

extern "C" void kernel_launch(void* const* d_in, const int* in_sizes, int n_in,
                              void* d_out, int out_size, void* d_ws, size_t ws_size,
                              hipStream_t stream) {
    const float* X          = (const float*)d_in[0];
    const float* comp_cv1_w = (const float*)d_in[1];
    const float* comp_cv1_s = (const float*)d_in[2];
    const float* comp_cv1_b = (const float*)d_in[3];
    const float* comp_dw3_w = (const float*)d_in[4];
    const float* comp_dw3_s = (const float*)d_in[5];
    const float* comp_dw3_b = (const float*)d_in[6];
    const float* comp_dw5_w = (const float*)d_in[7];
    const float* comp_dw5_s = (const float*)d_in[8];
    const float* comp_dw5_b = (const float*)d_in[9];
    const float* comp_px_w  = (const float*)d_in[10];
    const float* comp_px_s  = (const float*)d_in[11];
    const float* comp_px_b  = (const float*)d_in[12];
    const float* enc_cv1_w  = (const float*)d_in[13];
    const float* enc_cv1_s  = (const float*)d_in[14];
    const float* enc_cv1_b  = (const float*)d_in[15];
    const float* enc_dw3_w  = (const float*)d_in[16];
    const float* enc_dw3_s  = (const float*)d_in[17];
    const float* enc_dw3_b  = (const float*)d_in[18];
    const float* enc_dw5_w  = (const float*)d_in[19];
    const float* enc_dw5_s  = (const float*)d_in[20];
    const float* enc_dw5_b  = (const float*)d_in[21];
    const float* enc_px_w   = (const float*)d_in[22];
    const float* enc_px_s   = (const float*)d_in[23];
    const float* enc_px_b   = (const float*)d_in[24];
    float* out = (float*)d_out;

    const int B = 2, H = 64, W = 64, HW = H * W;
    float* x1c   = (float*)d_ws;                   // [B, 32, HW]
    float* yc    = x1c   + (size_t)B * 32 * HW;    // [B, 64, HW]
    float* cat_e = yc    + (size_t)B * 64 * HW;    // [B, 100, HW]
    float* wraw  = cat_e + (size_t)B * 100 * HW;   // [B, 100, HW]

    int pixBlocks = (B * HW + 255) / 256;   // 32

    // 1. comp cv1 (1x1, 128 -> 32)
    pw_conv_silu<4, 128><<<dim3(pixBlocks, 8), 256, 0, stream>>>(
        X, HW, B, comp_cv1_w, comp_cv1_s, comp_cv1_b, x1c, 32);

    // 2. comp dw + comp px (fusedA, 512 blocks)
    fusedA_kernel<<<dim3(64, 4, B), 256, 0, stream>>>(
        x1c,
        comp_dw3_w, comp_dw3_s, comp_dw3_b,
        comp_dw5_w, comp_dw5_s, comp_dw5_b,
        comp_px_w, comp_px_s, comp_px_b,
        yc);

    // 3. enc cv1 (1x1, 64 -> 50) into cat_e[0..49]
    pw_conv_silu<5, 64><<<dim3(pixBlocks, 10), 256, 0, stream>>>(
        yc, HW, B, enc_cv1_w, enc_cv1_s, enc_cv1_b, cat_e, 100);

    // 4. enc dw (1600 blocks, pixel-channel-parallel)
    {
        int n = B * 50 * HW;
        dw_conv_silu<<<(n + 255) / 256, 256, 0, stream>>>(
            cat_e, 25, H, W, 100, B,
            enc_dw3_w, enc_dw3_s, enc_dw3_b,
            enc_dw5_w, enc_dw5_s, enc_dw5_b);
    }

    // 5. enc px (1x1, 100 -> 100), raw weights
    pw_conv_silu<5, 100><<<dim3(pixBlocks, 20), 256, 0, stream>>>(
        cat_e, HW, B, enc_px_w, enc_px_s, enc_px_b, wraw, 100);

    // 6. CARAFE reassembly (softmax fused, in-register), 1024 blocks
    carafe_kernel<<<dim3(64, 8, B), 256, 0, stream>>>(X, wraw, out);
}

// Round 11
// 79.404 us; speedup vs baseline: 1.7635x; 1.1618x over previous
//
#include <hip/hip_runtime.h>
#include <math.h>

__device__ __forceinline__ float silu_act(float y) {
    return y / (1.f + __expf(-y));
}

// Pointwise 1x1 conv + scale/bias + SiLU. Compile-time Cin for full unroll.
// Weight rows block-uniform -> SGPR loads; lane = pixel -> coalesced.
template<int TC, int CIN>
__global__ void pw_conv_silu(const float* __restrict__ in, int HW, int B,
                             const float* __restrict__ w,
                             const float* __restrict__ sc, const float* __restrict__ bi,
                             float* __restrict__ out, int CoutStride) {
    int g = blockIdx.x * blockDim.x + threadIdx.x;
    if (g >= B * HW) return;
    int b = g / HW, pix = g - b * HW;
    int co0 = blockIdx.y * TC;
    float acc[TC];
#pragma unroll
    for (int j = 0; j < TC; ++j) acc[j] = 0.f;
    const float* ip = in + (size_t)b * CIN * HW + pix;
    const float* wp = w + (size_t)co0 * CIN;
#pragma unroll 8
    for (int ci = 0; ci < CIN; ++ci) {
        float v = ip[(size_t)ci * HW];
#pragma unroll
        for (int j = 0; j < TC; ++j)
            acc[j] = fmaf(v, wp[j * CIN + ci], acc[j]);
    }
#pragma unroll
    for (int j = 0; j < TC; ++j) {
        int co = co0 + j;
        float y = fmaf(acc[j], sc[co], bi[co]);
        out[((size_t)b * CoutStride + co) * HW + pix] = silu_act(y);
    }
}

// Fused depthwise 3x3 (channels [0,ch)) and 5x5 (channels [ch,2ch)) + SiLU.
__global__ void dw_conv_silu(float* __restrict__ cat, int ch, int H, int W, int Ctot, int B,
                             const float* __restrict__ w3, const float* __restrict__ s3,
                             const float* __restrict__ b3,
                             const float* __restrict__ w5, const float* __restrict__ s5,
                             const float* __restrict__ b5) {
    int HW = H * W;
    int idx = blockIdx.x * blockDim.x + threadIdx.x;
    int total = B * 2 * ch * HW;
    if (idx >= total) return;
    int pix = idx % HW;
    int t = idx / HW;
    int c2 = t % (2 * ch);
    int b = t / (2 * ch);
    int x = pix % W, y = pix / W;
    const float* ip = cat + ((size_t)b * Ctot + c2) * HW;
    float acc = 0.f, scale, bias;
    if (c2 < ch) {
        const float* wk = w3 + c2 * 9;
#pragma unroll
        for (int ky = 0; ky < 3; ++ky) {
            int iy = y + ky - 1;
            if ((unsigned)iy >= (unsigned)H) continue;
#pragma unroll
            for (int kx = 0; kx < 3; ++kx) {
                int ix = x + kx - 1;
                if ((unsigned)ix >= (unsigned)W) continue;
                acc = fmaf(ip[iy * W + ix], wk[ky * 3 + kx], acc);
            }
        }
        scale = s3[c2]; bias = b3[c2];
    } else {
        int c = c2 - ch;
        const float* wk = w5 + c * 25;
#pragma unroll
        for (int ky = 0; ky < 5; ++ky) {
            int iy = y + ky - 2;
            if ((unsigned)iy >= (unsigned)H) continue;
#pragma unroll
            for (int kx = 0; kx < 5; ++kx) {
                int ix = x + kx - 2;
                if ((unsigned)ix >= (unsigned)W) continue;
                acc = fmaf(ip[iy * W + ix], wk[ky * 5 + kx], acc);
            }
        }
        scale = s5[c]; bias = b5[c];
    }
    float v = fmaf(acc, scale, bias);
    cat[((size_t)b * Ctot + 2 * ch + c2) * HW + pix] = silu_act(v);
}

// fusedA (round-9-proven, ~7 us): comp dw3/dw5 + comp px (1x1).
__global__ __launch_bounds__(256) void fusedA_kernel(
        const float* __restrict__ x1c,
        const float* __restrict__ w3, const float* __restrict__ s3, const float* __restrict__ b3,
        const float* __restrict__ w5, const float* __restrict__ s5, const float* __restrict__ b5,
        const float* __restrict__ pxw, const float* __restrict__ pxs, const float* __restrict__ pxb,
        float* __restrict__ y) {
    const int H = 64, Wd = 64, HW = 4096;
    int Y = blockIdx.x, og = blockIdx.y, b = blockIdx.z;
    __shared__ float cat[64][64];
    int t = threadIdx.x;
    int l = t & 63;
    int w = __builtin_amdgcn_readfirstlane(t >> 6);
    const float* src = x1c + (size_t)b * 32 * HW;
#pragma unroll
    for (int k = 0; k < 8; ++k) {
        int c = w + 4 * k;
        const float* ip = src + (size_t)c * HW;
        float acc = 0.f, sc, bi;
        if (c < 16) {
            const float* wk = w3 + c * 9;
#pragma unroll
            for (int p = 0; p < 3; ++p) {
                int iy = Y + p - 1;
                if ((unsigned)iy >= (unsigned)H) continue;
#pragma unroll
                for (int kx = 0; kx < 3; ++kx) {
                    int ix = l + kx - 1;
                    if ((unsigned)ix >= (unsigned)Wd) continue;
                    acc = fmaf(ip[iy * Wd + ix], wk[p * 3 + kx], acc);
                }
            }
            sc = s3[c]; bi = b3[c];
        } else {
            const float* wk = w5 + (c - 16) * 25;
#pragma unroll
            for (int p = 0; p < 5; ++p) {
                int iy = Y + p - 2;
                if ((unsigned)iy >= (unsigned)H) continue;
#pragma unroll
                for (int kx = 0; kx < 5; ++kx) {
                    int ix = l + kx - 2;
                    if ((unsigned)ix >= (unsigned)Wd) continue;
                    acc = fmaf(ip[iy * Wd + ix], wk[p * 5 + kx], acc);
                }
            }
            sc = s5[c - 16]; bi = b5[c - 16];
        }
        cat[c][l] = ip[Y * Wd + l];
        cat[32 + c][l] = silu_act(fmaf(acc, sc, bi));
    }
    __syncthreads();
    {
        int co0 = og * 16 + w * 4;
        const float* wp = pxw + (size_t)co0 * 64;
        float acc[4] = {0.f, 0.f, 0.f, 0.f};
#pragma unroll 8
        for (int ci = 0; ci < 64; ++ci) {
            float xv = cat[ci][l];
#pragma unroll
            for (int k = 0; k < 4; ++k)
                acc[k] = fmaf(xv, wp[k * 64 + ci], acc[k]);
        }
#pragma unroll
        for (int k = 0; k < 4; ++k) {
            int co = co0 + k;
            y[((size_t)b * 64 + co) * HW + Y * Wd + l] =
                silu_act(fmaf(acc[k], pxs[co], pxb[co]));
        }
    }
}

// CARAFE v6: spill-free. Thread = (l = ox-pair, rp = t>>6 output quadrant).
// Each thread: 25 weights in regs (ONLY its rp), in-register softmax, then
// 8 channels x 1 output pixel. Block = (Y, 8-ch chunk, b) -> 2048 blocks,
// LDS 10.9 KB, ~64 VGPR -> no scratch, 8 blocks/CU.
__global__ __launch_bounds__(256) void carafe_kernel(
        const float* __restrict__ X, const float* __restrict__ wraw,
        float* __restrict__ out) {
    const int H = 64, Wd = 64, C = 128, Ho = 128, Wo = 128, HW = H * Wd;
    int Y = blockIdx.x;           // 0..63
    int cchunk = blockIdx.y;      // 0..15 (8 channels each)
    int b = blockIdx.z;
    __shared__ float xs[8][5][68];    // zero-padded cols: col = ix+2
    int t = threadIdx.x;
    int c0 = cchunk * 8;
    const float* Xb = X + ((size_t)b * C + c0) * HW;
    for (int i = t; i < 8 * 5 * 68; i += 256) {
        int col = i % 68;
        int tmp = i / 68;
        int p = tmp % 5;
        int c = tmp / 5;
        int iy = Y + p - 2, ix = col - 2;
        float v = 0.f;
        if ((unsigned)iy < (unsigned)H && (unsigned)ix < (unsigned)Wd)
            v = Xb[(size_t)c * HW + iy * Wd + ix];
        xs[c][p][col] = v;
    }
    int l = t & 63;               // ox-pair: Xc = l
    int rp = t >> 6;              // 0..3: oy-offset = rp>>1, ox-parity = rp&1
    // load this thread's 25 raw weights (coalesced over l): chW = j*4 + rp
    const float* wb = wraw + (size_t)b * 100 * HW + Y * Wd + l;
    float wreg[25];
#pragma unroll
    for (int j = 0; j < 25; ++j)
        wreg[j] = wb[(size_t)(j * 4 + rp) * HW];
    // in-register softmax over the 25 taps
    {
        float m = -1e30f;
#pragma unroll
        for (int j = 0; j < 25; ++j) m = fmaxf(m, wreg[j]);
        float s = 0.f;
#pragma unroll
        for (int j = 0; j < 25; ++j) { wreg[j] = __expf(wreg[j] - m); s += wreg[j]; }
        float inv = 1.f / s;
#pragma unroll
        for (int j = 0; j < 25; ++j) wreg[j] *= inv;
    }
    __syncthreads();

    int oy = 2 * Y + (rp >> 1);
    int ox = 2 * l + (rp & 1);
#pragma unroll
    for (int k = 0; k < 8; ++k) {
        float acc = 0.f;
#pragma unroll
        for (int p = 0; p < 5; ++p)
#pragma unroll
            for (int q = 0; q < 5; ++q)
                acc = fmaf(wreg[p * 5 + q], xs[k][p][l + q], acc);
        out[(((size_t)b * C + (c0 + k)) * Ho + oy) * Wo + ox] = acc;
    }
}

extern "C" void kernel_launch(void* const* d_in, const int* in_sizes, int n_in,
                              void* d_out, int out_size, void* d_ws, size_t ws_size,
                              hipStream_t stream) {
    const float* X          = (const float*)d_in[0];
    const float* comp_cv1_w = (const float*)d_in[1];
    const float* comp_cv1_s = (const float*)d_in[2];
    const float* comp_cv1_b = (const float*)d_in[3];
    const float* comp_dw3_w = (const float*)d_in[4];
    const float* comp_dw3_s = (const float*)d_in[5];
    const float* comp_dw3_b = (const float*)d_in[6];
    const float* comp_dw5_w = (const float*)d_in[7];
    const float* comp_dw5_s = (const float*)d_in[8];
    const float* comp_dw5_b = (const float*)d_in[9];
    const float* comp_px_w  = (const float*)d_in[10];
    const float* comp_px_s  = (const float*)d_in[11];
    const float* comp_px_b  = (const float*)d_in[12];
    const float* enc_cv1_w  = (const float*)d_in[13];
    const float* enc_cv1_s  = (const float*)d_in[14];
    const float* enc_cv1_b  = (const float*)d_in[15];
    const float* enc_dw3_w  = (const float*)d_in[16];
    const float* enc_dw3_s  = (const float*)d_in[17];
    const float* enc_dw3_b  = (const float*)d_in[18];
    const float* enc_dw5_w  = (const float*)d_in[19];
    const float* enc_dw5_s  = (const float*)d_in[20];
    const float* enc_dw5_b  = (const float*)d_in[21];
    const float* enc_px_w   = (const float*)d_in[22];
    const float* enc_px_s   = (const float*)d_in[23];
    const float* enc_px_b   = (const float*)d_in[24];
    float* out = (float*)d_out;

    const int B = 2, H = 64, W = 64, HW = H * W;
    float* x1c   = (float*)d_ws;                   // [B, 32, HW]
    float* yc    = x1c   + (size_t)B * 32 * HW;    // [B, 64, HW]
    float* cat_e = yc    + (size_t)B * 64 * HW;    // [B, 100, HW]
    float* wraw  = cat_e + (size_t)B * 100 * HW;   // [B, 100, HW]

    int pixBlocks = (B * HW + 255) / 256;   // 32

    // 1. comp cv1 (1x1, 128 -> 32)
    pw_conv_silu<4, 128><<<dim3(pixBlocks, 8), 256, 0, stream>>>(
        X, HW, B, comp_cv1_w, comp_cv1_s, comp_cv1_b, x1c, 32);

    // 2. comp dw + comp px (fusedA, 512 blocks)
    fusedA_kernel<<<dim3(64, 4, B), 256, 0, stream>>>(
        x1c,
        comp_dw3_w, comp_dw3_s, comp_dw3_b,
        comp_dw5_w, comp_dw5_s, comp_dw5_b,
        comp_px_w, comp_px_s, comp_px_b,
        yc);

    // 3. enc cv1 (1x1, 64 -> 50) into cat_e[0..49]
    pw_conv_silu<5, 64><<<dim3(pixBlocks, 10), 256, 0, stream>>>(
        yc, HW, B, enc_cv1_w, enc_cv1_s, enc_cv1_b, cat_e, 100);

    // 4. enc dw (1600 blocks, pixel-channel-parallel)
    {
        int n = B * 50 * HW;
        dw_conv_silu<<<(n + 255) / 256, 256, 0, stream>>>(
            cat_e, 25, H, W, 100, B,
            enc_dw3_w, enc_dw3_s, enc_dw3_b,
            enc_dw5_w, enc_dw5_s, enc_dw5_b);
    }

    // 5. enc px (1x1, 100 -> 100), raw weights
    pw_conv_silu<5, 100><<<dim3(pixBlocks, 20), 256, 0, stream>>>(
        cat_e, HW, B, enc_px_w, enc_px_s, enc_px_b, wraw, 100);

    // 6. CARAFE v6 (spill-free, softmax in-register), 2048 blocks
    carafe_kernel<<<dim3(64, 16, B), 256, 0, stream>>>(X, wraw, out);
}